// Round 10
// baseline (458.985 us; speedup 1.0000x reference)
//
#include <hip/hip_runtime.h>
#include <hip/hip_bf16.h>
#include <stdint.h>

// ---------------------------------------------------------------------------
// Pipeline (K padded 1568 -> 1600 so BK=64 divides; pad cols are zeros):
//  KP prep012 (merged):
//    - K1 part: ws.x_bf[:, :784] = bf16((xd@W_lp^T + b_lp - .5)/.2)
//    - K2 part: ws.x_bf[:, 784:1568] = bf16((xr - .5)/.2); pad = 0
//    - K0 part: ws.Wnet_bf[r][0:1568] = bf16(W_net[r]); [1568:1600]=0
//  K3 gemm_mfma_256:  d_out = (x_bf @ Wnet_bf^T + b_net)*0.2   [2048,25088] f32
//                     256x224 tile (grid 896 = 3.5*256), BK=64, 8 waves,
//                     2-buffer LDS, ONE __syncthreads per K64-tile,
//                     XOR-swizzled LDS (0 conflicts), XCD bands.
//  K4a gram_solve:    per batch: G = W W^T via REGISTER-DIRECT MFMA (global
//                     f32 -> cvt -> mfma; reverted to round-8 version),
//                     L = chol(G), M = diag(L) L^-1 -> ws
//  K4b gs_apply:      ONE block per batch: M staged once, 7 column-chunks
//                     looped; out_i = w_i + sum_{j<i} M_ij w_j, balanced rows
// ---------------------------------------------------------------------------

typedef short s16x8 __attribute__((ext_vector_type(8)));
typedef float f32x4 __attribute__((ext_vector_type(4)));

#define GL_LDS16(gptr, lptr)                                                   \
    __builtin_amdgcn_global_load_lds(                                          \
        (const __attribute__((address_space(1))) void*)(gptr),                 \
        (__attribute__((address_space(3))) void*)(lptr), 16, 0, 0)

#define KP 1600   // padded K

// ========================= K3: 256x224 MFMA GEMM ===========================
// (unchanged from round 7 — see comments there)
__global__ __launch_bounds__(512, 1) void gemm_mfma_256(
    const __hip_bfloat16* __restrict__ A, const __hip_bfloat16* __restrict__ B,
    const float* __restrict__ bias, float* __restrict__ C,
    int M, int N, int K)
{
    __shared__ __align__(16) short lds[2][30720];   // 2 x 60 KB

    const int t = threadIdx.x;
    const int l = t & 63;
    const int wv = t >> 6;          // wave 0..7
    const int wm = wv >> 1;         // M-band 0..3 (64 rows)
    const int wn = wv & 1;          // N-half 0..1 (112 cols)

    const int f  = blockIdx.x;      // grid = 896 = 8 * 112
    const int xb = f >> 3;
    const int yb = f & 7;
    const int m0 = yb * 256;
    const int n0 = xb * 224;

    const short* As = (const short*)A;
    const short* Bs = (const short*)B;

    const bool isA = wv < 4;
    const int colE = (((l & 7) ^ (l >> 3)) << 3);
    const size_t srcRow = isA ? (size_t)(m0 + wv * 64 + (l >> 3))
                              : (size_t)(n0 + (wv - 4) * 56 + (l >> 3));
    const size_t src0 = srcRow * KP + colE;
    const short* gsrc = isA ? As : Bs;
    const int dstBase = isA ? wv * 4096 : 16384 + (wv - 4) * 3584;

    const int sk0 = ((l >> 4) << 3) ^ ((l & 7) << 3);   // ks=0 swizzled col
    const int sk1 = sk0 ^ 32;                            // ks=1
    const int aoff = (wm * 64 + (l & 15)) * 64;
    const int boff = 16384 + (wn * 112 + (l & 15)) * 64;

    f32x4 acc[4][7] = {};

#define STAGE_TILE(buf, T)                                                     \
    do {                                                                       \
        short* d_ = &lds[buf][dstBase];                                        \
        const short* s_ = gsrc + src0 + (size_t)(T) * 64;                      \
        GL_LDS16(s_ + (size_t)0 * 8 * KP, d_ + 0 * 512);                       \
        GL_LDS16(s_ + (size_t)1 * 8 * KP, d_ + 1 * 512);                       \
        GL_LDS16(s_ + (size_t)2 * 8 * KP, d_ + 2 * 512);                       \
        GL_LDS16(s_ + (size_t)3 * 8 * KP, d_ + 3 * 512);                       \
        GL_LDS16(s_ + (size_t)4 * 8 * KP, d_ + 4 * 512);                       \
        GL_LDS16(s_ + (size_t)5 * 8 * KP, d_ + 5 * 512);                       \
        GL_LDS16(s_ + (size_t)6 * 8 * KP, d_ + 6 * 512);                       \
        if (isA) GL_LDS16(s_ + (size_t)7 * 8 * KP, d_ + 7 * 512);              \
    } while (0)

    const int NT = K >> 6;          // 25
    STAGE_TILE(0, 0);
    __syncthreads();                // drains vmcnt(0): tile 0 ready

    for (int kt = 0; kt < NT; ++kt) {
        const int cur = kt & 1;
        const short* bufc = &lds[cur][0];

        if (kt + 1 < NT) STAGE_TILE(cur ^ 1, kt + 1);

        s16x8 bfr[7][2];
        #pragma unroll
        for (int ni = 0; ni < 7; ++ni) {
            bfr[ni][0] = *(const s16x8*)&bufc[boff + ni * 1024 + sk0];
            bfr[ni][1] = *(const s16x8*)&bufc[boff + ni * 1024 + sk1];
        }

        #pragma unroll
        for (int mi = 0; mi < 4; ++mi) {
            s16x8 a0 = *(const s16x8*)&bufc[aoff + mi * 1024 + sk0];
            s16x8 a1 = *(const s16x8*)&bufc[aoff + mi * 1024 + sk1];
            __builtin_amdgcn_s_setprio(1);
            #pragma unroll
            for (int ni = 0; ni < 7; ++ni) {
                acc[mi][ni] = __builtin_amdgcn_mfma_f32_16x16x32_bf16(
                    a0, bfr[ni][0], acc[mi][ni], 0, 0, 0);
                acc[mi][ni] = __builtin_amdgcn_mfma_f32_16x16x32_bf16(
                    a1, bfr[ni][1], acc[mi][ni], 0, 0, 0);
            }
            __builtin_amdgcn_s_setprio(0);
        }

        __syncthreads();
    }
#undef STAGE_TILE

    const int row0 = m0 + wm * 64 + ((l >> 4) << 2);
    const int col0 = n0 + wn * 112 + (l & 15);
    #pragma unroll
    for (int ni = 0; ni < 7; ++ni) {
        const int n = col0 + ni * 16;
        const float bn = bias[n];
        #pragma unroll
        for (int mi = 0; mi < 4; ++mi) {
            const int r0 = row0 + mi * 16;
            #pragma unroll
            for (int r = 0; r < 4; ++r)
                C[(size_t)(r0 + r) * N + n] = (acc[mi][ni][r] + bn) * 0.2f;
        }
    }
}

// ================= prep012: merged K1 + K2 + K0 ============================
#define TILE_M 64
#define TILE_N 64
#define TILE_K 16
#define LDS_STRIDE 72
#define NB_K1 416        // 13 x 32 tiles
#define NB_K2 2048
#define NB_K0 25088

__global__ __launch_bounds__(256) void prep012(
    const float* __restrict__ xd, const float* __restrict__ xr,
    const float* __restrict__ Wlp, const float* __restrict__ blp,
    const float* __restrict__ Wnet,
    __hip_bfloat16* __restrict__ Wnet_bf, __hip_bfloat16* __restrict__ x_bf)
{
    const int bid = blockIdx.x;
    const int t = threadIdx.x;

    if (bid < NB_K1) {
        // ---- K1: x_bf[:, :784] = bf16((xd @ Wlp^T + blp - .5)/.2) ----
        __shared__ float As[TILE_K][LDS_STRIDE];
        __shared__ float Bsh[TILE_K][LDS_STRIDE];

        const int bx = bid % 13, by = bid / 13;
        const int tx = t & 15;
        const int ty = t >> 4;
        const int m0 = by * TILE_M;
        const int n0 = bx * TILE_N;
        const int lrow = t >> 2;
        const int lk   = (t & 3) << 2;
        const int Kd = 832, Nd = 784;

        float acc[4][4] = {};

        for (int kt = 0; kt < Kd; kt += TILE_K) {
            float4 av = *(const float4*)(xd + (size_t)(m0 + lrow) * Kd + kt + lk);
            float4 bv = make_float4(0.f, 0.f, 0.f, 0.f);
            if (n0 + lrow < Nd)
                bv = *(const float4*)(Wlp + (size_t)(n0 + lrow) * Kd + kt + lk);

            __syncthreads();
            As[lk + 0][lrow] = av.x; As[lk + 1][lrow] = av.y;
            As[lk + 2][lrow] = av.z; As[lk + 3][lrow] = av.w;
            Bsh[lk + 0][lrow] = bv.x; Bsh[lk + 1][lrow] = bv.y;
            Bsh[lk + 2][lrow] = bv.z; Bsh[lk + 3][lrow] = bv.w;
            __syncthreads();

            #pragma unroll
            for (int k = 0; k < TILE_K; ++k) {
                float4 a = *(const float4*)&As[k][ty << 2];
                float4 b = *(const float4*)&Bsh[k][tx << 2];
                acc[0][0] += a.x * b.x; acc[0][1] += a.x * b.y;
                acc[0][2] += a.x * b.z; acc[0][3] += a.x * b.w;
                acc[1][0] += a.y * b.x; acc[1][1] += a.y * b.y;
                acc[1][2] += a.y * b.z; acc[1][3] += a.y * b.w;
                acc[2][0] += a.z * b.x; acc[2][1] += a.z * b.y;
                acc[2][2] += a.z * b.z; acc[2][3] += a.z * b.w;
                acc[3][0] += a.w * b.x; acc[3][1] += a.w * b.y;
                acc[3][2] += a.w * b.z; acc[3][3] += a.w * b.w;
            }
        }

        #pragma unroll
        for (int j = 0; j < 4; ++j) {
            int n = n0 + (tx << 2) + j;
            if (n < Nd) {
                float bn = blp[n];
                #pragma unroll
                for (int i = 0; i < 4; ++i) {
                    float v = (acc[i][j] + bn - 0.5f) / 0.2f;
                    x_bf[(size_t)(m0 + (ty << 2) + i) * KP + n] =
                        __float2bfloat16(v);
                }
            }
        }
    } else if (bid < NB_K1 + NB_K2) {
        // ---- K2: x_bf[:, 784:1568] = bf16((xr - .5)/.2); pad zeros ----
        const int b = bid - NB_K1;
        if (t < 196) {
            float4 v = *(const float4*)(xr + (size_t)b * 784 + (t << 2));
            __hip_bfloat16 o[4] = {
                __float2bfloat16((v.x - 0.5f) / 0.2f),
                __float2bfloat16((v.y - 0.5f) / 0.2f),
                __float2bfloat16((v.z - 0.5f) / 0.2f),
                __float2bfloat16((v.w - 0.5f) / 0.2f)};
            *(ushort4*)&x_bf[(size_t)b * KP + 784 + (t << 2)] =
                *(const ushort4*)o;
        } else if (t < 204) {
            *(ushort4*)&x_bf[(size_t)b * KP + 1568 + ((t - 196) << 2)] =
                make_ushort4(0, 0, 0, 0);
        }
    } else {
        // ---- K0: Wnet_bf[r][0:1568] = bf16(Wnet[r]); pad zeros ----
        const size_t r = bid - (NB_K1 + NB_K2);
        const float* src = Wnet + r * 1568;
        __hip_bfloat16* dst = Wnet_bf + r * KP;

        for (int i = t; i < 392; i += 256) {
            float4 v = *(const float4*)(src + (i << 2));
            __hip_bfloat16 o[4] = {
                __float2bfloat16(v.x), __float2bfloat16(v.y),
                __float2bfloat16(v.z), __float2bfloat16(v.w)};
            *(ushort4*)&dst[i << 2] = *(const ushort4*)o;
        }
        if (t < 8)
            *(ushort4*)&dst[1568 + (t << 2)] = make_ushort4(0, 0, 0, 0);
    }
}

// ==================== K4a: Gram + Cholesky solve ===========================
// Gram via register-direct MFMA (round-8 version): each wave computes one
// 16x16 quadrant of G = W W^T reading f32 fragments straight from global
// (L2-resident: 100 KB per block), converting to bf16 in-reg. No LDS
// staging, no barriers in the Gram loop. Then Cholesky + substitution.
#define GS_N 32
#define GS_D 784

__device__ __forceinline__ s16x8 cvt8(float4 a, float4 b) {
    __hip_bfloat16 h[8] = {
        __float2bfloat16(a.x), __float2bfloat16(a.y),
        __float2bfloat16(a.z), __float2bfloat16(a.w),
        __float2bfloat16(b.x), __float2bfloat16(b.y),
        __float2bfloat16(b.z), __float2bfloat16(b.w)};
    return *(const s16x8*)h;
}

__global__ __launch_bounds__(256, 4) void gram_solve(
    const float* __restrict__ out, float* __restrict__ Mws)
{
    __shared__ float Gs[GS_N][GS_N + 1];            // 4224 B (G -> L)
    __shared__ float Ms[GS_N][GS_N + 1];            // 4224 B
    __shared__ float Ld[GS_N];

    const int t = threadIdx.x;
    const int l = t & 63;
    const int w = t >> 6;
    const float* row0 = out + (size_t)blockIdx.x * (GS_N * GS_D);

    const int wr = w >> 1, wc2 = w & 1;
    const int ra = wr * 16 + (l & 15);   // Gram row index (A operand)
    const int rb = wc2 * 16 + (l & 15);  // Gram col index (B operand)
    const int kg = l >> 4;               // k-subgroup 0..3

    const float* pa = row0 + (size_t)ra * GS_D + kg * 8;
    const float* pb = row0 + (size_t)rb * GS_D + kg * 8;

    f32x4 acc = {};
    #pragma unroll 2
    for (int s = 0; s < 24; ++s) {       // 24 full K32 steps (768 cols)
        float4 a0 = *(const float4*)(pa + s * 32);
        float4 a1 = *(const float4*)(pa + s * 32 + 4);
        float4 b0 = *(const float4*)(pb + s * 32);
        float4 b1 = *(const float4*)(pb + s * 32 + 4);
        acc = __builtin_amdgcn_mfma_f32_16x16x32_bf16(
            cvt8(a0, a1), cvt8(b0, b1), acc, 0, 0, 0);
    }
    {                                    // tail cols 768..783: kg 0,1 valid
        s16x8 af = {}, bf = {};
        if (kg < 2) {
            float4 a0 = *(const float4*)(pa + 768);
            float4 a1 = *(const float4*)(pa + 768 + 4);
            float4 b0 = *(const float4*)(pb + 768);
            float4 b1 = *(const float4*)(pb + 768 + 4);
            af = cvt8(a0, a1); bf = cvt8(b0, b1);
        }
        acc = __builtin_amdgcn_mfma_f32_16x16x32_bf16(af, bf, acc, 0, 0, 0);
    }

    // C/D layout: col = lane&15, row = (lane>>4)*4 + reg
    {
        const int di = wr * 16 + (l >> 4) * 4;
        const int dj = wc2 * 16 + (l & 15);
        #pragma unroll
        for (int r = 0; r < 4; ++r) Gs[di + r][dj] = acc[r];
    }
    for (int z = t; z < GS_N * (GS_N + 1); z += 256) ((float*)Ms)[z] = 0.f;
    __syncthreads();

    // Cholesky, lower triangle in place (diag in Ld)
    for (int k = 0; k < GS_N; ++k) {
        const float sk = sqrtf(Gs[k][k]);
        if (t == k) Ld[k] = sk;
        if (t > k && t < GS_N) Gs[t][k] /= sk;
        __syncthreads();
        if (t > k && t < GS_N) {
            const float lik = Gs[t][k];
            for (int j = k + 1; j <= t; ++j)
                Gs[t][j] -= lik * Gs[j][k];
        }
        __syncthreads();
    }

    // M = diag(L) * L^-1, column-parallel forward substitution
    if (t < GS_N) {
        const int j = t;
        Ms[j][j] = 1.0f / Ld[j];
        for (int i = j + 1; i < GS_N; ++i) {
            float a = 0.f;
            for (int k = j; k < i; ++k)
                a += Gs[i][k] * Ms[k][j];
            Ms[i][j] = -a / Ld[i];
        }
        for (int i = j + 1; i < GS_N; ++i)
            Ms[i][j] *= Ld[i];
    }
    __syncthreads();

    {
        const int i = t >> 3, j0 = (t & 7) << 2;
        float4 mv = make_float4(Ms[i][j0], Ms[i][j0 + 1],
                                Ms[i][j0 + 2], Ms[i][j0 + 3]);
        *(float4*)(Mws + (size_t)blockIdx.x * 1024 + (t << 2)) = mv;
    }
}

// ======================= K4b: apply correction =============================
// ONE block per batch: stage M once (was 7x), loop the 7 column-chunks.
// Chunks are column-disjoint (reads/writes of different chunks never alias).
// Balanced rows per thread-group g = t>>5: {g, 31-g, 15-g, 16+g}; two shared
// j-loops of lengths (31-g) and (16+g) -> uniform 47 iters for every thread.
__global__ __launch_bounds__(256, 8) void gs_apply(
    float* __restrict__ out, const float* __restrict__ Mws)
{
    __shared__ float4 Wf[GS_N][28];     // 14336 B (f32 chunk)
    __shared__ float  Ml[GS_N][36];     // 4608 B (padded for f4 writes)

    const int t = threadIdx.x;
    const int b = blockIdx.x;
    float* row0 = out + (size_t)b * (GS_N * GS_D);

    {
        float4 mv = *(const float4*)(Mws + (size_t)b * 1024 + (t << 2));
        const int i = t >> 3, j0 = (t & 7) << 2;
        *(float4*)&Ml[i][j0] = mv;
    }

    const int g  = t >> 5;              // 0..7
    const int c4 = t & 31;              // float4 column
    const int rA = g, rB = 31 - g, rC = 15 - g, rD = 16 + g;

    for (int ch = 0; ch < 7; ++ch) {
        const int k0 = ch * 112;
        __syncthreads();                // Ml ready / prev chunk's reads done
        #pragma unroll
        for (int hh = 0; hh < 4; ++hh) {
            const int h = t + hh * 256; // 0..1023
            const int r = h >> 5, c = h & 31;
            if (c < 28)
                Wf[r][c] = *(const float4*)(row0 + r * GS_D + k0 + (c << 2));
        }
        __syncthreads();

        if (c4 < 28) {
            float4 vA = Wf[rA][c4];
            float4 vB = Wf[rB][c4];
            float4 vC = Wf[rC][c4];
            float4 vD = Wf[rD][c4];
            for (int j = 0; j < rB; ++j) {
                const float4 wj = Wf[j][c4];
                const float mA = (j < rA) ? Ml[rA][j] : 0.f;
                const float mB = Ml[rB][j];
                vA.x += mA * wj.x; vA.y += mA * wj.y;
                vA.z += mA * wj.z; vA.w += mA * wj.w;
                vB.x += mB * wj.x; vB.y += mB * wj.y;
                vB.z += mB * wj.z; vB.w += mB * wj.w;
            }
            for (int j = 0; j < rD; ++j) {
                const float4 wj = Wf[j][c4];
                const float mC = (j < rC) ? Ml[rC][j] : 0.f;
                const float mD = Ml[rD][j];
                vC.x += mC * wj.x; vC.y += mC * wj.y;
                vC.z += mC * wj.z; vC.w += mC * wj.w;
                vD.x += mD * wj.x; vD.y += mD * wj.y;
                vD.z += mD * wj.z; vD.w += mD * wj.w;
            }
            *(float4*)(row0 + rA * GS_D + k0 + (c4 << 2)) = vA;
            *(float4*)(row0 + rB * GS_D + k0 + (c4 << 2)) = vB;
            *(float4*)(row0 + rC * GS_D + k0 + (c4 << 2)) = vC;
            *(float4*)(row0 + rD * GS_D + k0 + (c4 << 2)) = vD;
        }
    }
}

// ================================ launch ===================================
extern "C" void kernel_launch(void* const* d_in, const int* in_sizes, int n_in,
                              void* d_out, int out_size, void* d_ws, size_t ws_size,
                              hipStream_t stream)
{
    const float* xd   = (const float*)d_in[0];  // [2048, 832]
    const float* xr   = (const float*)d_in[1];  // [2048, 1, 28, 28]
    const float* Wlp  = (const float*)d_in[2];  // [784, 832]
    const float* blp  = (const float*)d_in[3];  // [784]
    const float* Wnet = (const float*)d_in[4];  // [25088, 1568]
    const float* bnet = (const float*)d_in[5];  // [25088]
    float* out = (float*)d_out;                 // [2048, 32, 784] f32

    const int B = 2048, OUT = 32 * 784;

    // workspace: [Wnet_bf: 25088*1600*2 = 80.28 MB][x_bf: 2048*1600*2 = 6.55 MB]
    __hip_bfloat16* Wnet_bf = (__hip_bfloat16*)d_ws;
    __hip_bfloat16* x_bf =
        (__hip_bfloat16*)((char*)d_ws + (size_t)OUT * KP * 2);
    // M workspace overlays Wnet_bf region (free after K3; stream-ordered).
    float* Mws = (float*)d_ws;                  // [2048][32][32] f32 = 8.4 MB

    // prep: merged K1 (tiles first) + K2 + K0
    prep012<<<NB_K1 + NB_K2 + NB_K0, 256, 0, stream>>>(
        xd, xr, Wlp, blp, Wnet, Wnet_bf, x_bf);

    // K3: big MFMA GEMM -> d_out (fp32); grid 896 = 8 XCD bands x 112 panels
    gemm_mfma_256<<<dim3(896), 512, 0, stream>>>(
        x_bf, Wnet_bf, bnet, out, B, OUT, KP);

    // K4a: per-batch Gram (register-direct) + Cholesky -> M
    gram_solve<<<B, 256, 0, stream>>>(out, Mws);

    // K4b: apply rank-32 correction in place (1 block/batch, 7 chunks)
    gs_apply<<<B, 256, 0, stream>>>(out, Mws);
}

// Round 11
// 440.270 us; speedup vs baseline: 1.0425x; 1.0425x over previous
//
#include <hip/hip_runtime.h>
#include <hip/hip_bf16.h>
#include <stdint.h>

// ---------------------------------------------------------------------------
// Pipeline (K padded 1568 -> 1600 so BK=64 divides; pad cols are zeros):
//  KP prep012 (merged):
//    - K1 part: ws.x_bf[:, :784] = bf16((xd@W_lp^T + b_lp - .5)/.2)
//    - K2 part: ws.x_bf[:, 784:1568] = bf16((xr - .5)/.2); pad = 0
//    - K0 part: ws.Wnet_bf[r][0:1568] = bf16(W_net[r]); [1568:1600]=0
//  K3 gemm_mfma_256:  d_out = (x_bf @ Wnet_bf^T + b_net)*0.2   [2048,25088] f32
//                     256x224 tile (grid 896 = 3.5*256), BK=64, 8 waves,
//                     2-buffer LDS, ONE __syncthreads per K64-tile,
//                     XOR-swizzled LDS (0 conflicts), XCD bands.
//                     [structure ceiling: 3 schedule variants null; 2-blk/CU
//                      register-infeasible at this acc size]
//  K4a gram_solve:    per batch: G = W W^T via REGISTER-DIRECT MFMA (global
//                     f32 -> cvt -> mfma), L = chol(G), M = diag(L) L^-1 -> ws
//  K4b gs_apply:      7x2048 independent blocks (r8 config — measured best;
//                     in-block chunk loop regressed r10): out_i = w_i +
//                     sum_{j<i} M_ij w_j, balanced row sets
// ---------------------------------------------------------------------------

typedef short s16x8 __attribute__((ext_vector_type(8)));
typedef float f32x4 __attribute__((ext_vector_type(4)));

#define GL_LDS16(gptr, lptr)                                                   \
    __builtin_amdgcn_global_load_lds(                                          \
        (const __attribute__((address_space(1))) void*)(gptr),                 \
        (__attribute__((address_space(3))) void*)(lptr), 16, 0, 0)

#define KP 1600   // padded K

// ========================= K3: 256x224 MFMA GEMM ===========================
// (unchanged from round 7 — see comments there)
__global__ __launch_bounds__(512, 1) void gemm_mfma_256(
    const __hip_bfloat16* __restrict__ A, const __hip_bfloat16* __restrict__ B,
    const float* __restrict__ bias, float* __restrict__ C,
    int M, int N, int K)
{
    __shared__ __align__(16) short lds[2][30720];   // 2 x 60 KB

    const int t = threadIdx.x;
    const int l = t & 63;
    const int wv = t >> 6;          // wave 0..7
    const int wm = wv >> 1;         // M-band 0..3 (64 rows)
    const int wn = wv & 1;          // N-half 0..1 (112 cols)

    const int f  = blockIdx.x;      // grid = 896 = 8 * 112
    const int xb = f >> 3;
    const int yb = f & 7;
    const int m0 = yb * 256;
    const int n0 = xb * 224;

    const short* As = (const short*)A;
    const short* Bs = (const short*)B;

    const bool isA = wv < 4;
    const int colE = (((l & 7) ^ (l >> 3)) << 3);
    const size_t srcRow = isA ? (size_t)(m0 + wv * 64 + (l >> 3))
                              : (size_t)(n0 + (wv - 4) * 56 + (l >> 3));
    const size_t src0 = srcRow * KP + colE;
    const short* gsrc = isA ? As : Bs;
    const int dstBase = isA ? wv * 4096 : 16384 + (wv - 4) * 3584;

    const int sk0 = ((l >> 4) << 3) ^ ((l & 7) << 3);   // ks=0 swizzled col
    const int sk1 = sk0 ^ 32;                            // ks=1
    const int aoff = (wm * 64 + (l & 15)) * 64;
    const int boff = 16384 + (wn * 112 + (l & 15)) * 64;

    f32x4 acc[4][7] = {};

#define STAGE_TILE(buf, T)                                                     \
    do {                                                                       \
        short* d_ = &lds[buf][dstBase];                                        \
        const short* s_ = gsrc + src0 + (size_t)(T) * 64;                      \
        GL_LDS16(s_ + (size_t)0 * 8 * KP, d_ + 0 * 512);                       \
        GL_LDS16(s_ + (size_t)1 * 8 * KP, d_ + 1 * 512);                       \
        GL_LDS16(s_ + (size_t)2 * 8 * KP, d_ + 2 * 512);                       \
        GL_LDS16(s_ + (size_t)3 * 8 * KP, d_ + 3 * 512);                       \
        GL_LDS16(s_ + (size_t)4 * 8 * KP, d_ + 4 * 512);                       \
        GL_LDS16(s_ + (size_t)5 * 8 * KP, d_ + 5 * 512);                       \
        GL_LDS16(s_ + (size_t)6 * 8 * KP, d_ + 6 * 512);                       \
        if (isA) GL_LDS16(s_ + (size_t)7 * 8 * KP, d_ + 7 * 512);              \
    } while (0)

    const int NT = K >> 6;          // 25
    STAGE_TILE(0, 0);
    __syncthreads();                // drains vmcnt(0): tile 0 ready

    for (int kt = 0; kt < NT; ++kt) {
        const int cur = kt & 1;
        const short* bufc = &lds[cur][0];

        if (kt + 1 < NT) STAGE_TILE(cur ^ 1, kt + 1);

        s16x8 bfr[7][2];
        #pragma unroll
        for (int ni = 0; ni < 7; ++ni) {
            bfr[ni][0] = *(const s16x8*)&bufc[boff + ni * 1024 + sk0];
            bfr[ni][1] = *(const s16x8*)&bufc[boff + ni * 1024 + sk1];
        }

        #pragma unroll
        for (int mi = 0; mi < 4; ++mi) {
            s16x8 a0 = *(const s16x8*)&bufc[aoff + mi * 1024 + sk0];
            s16x8 a1 = *(const s16x8*)&bufc[aoff + mi * 1024 + sk1];
            __builtin_amdgcn_s_setprio(1);
            #pragma unroll
            for (int ni = 0; ni < 7; ++ni) {
                acc[mi][ni] = __builtin_amdgcn_mfma_f32_16x16x32_bf16(
                    a0, bfr[ni][0], acc[mi][ni], 0, 0, 0);
                acc[mi][ni] = __builtin_amdgcn_mfma_f32_16x16x32_bf16(
                    a1, bfr[ni][1], acc[mi][ni], 0, 0, 0);
            }
            __builtin_amdgcn_s_setprio(0);
        }

        __syncthreads();
    }
#undef STAGE_TILE

    const int row0 = m0 + wm * 64 + ((l >> 4) << 2);
    const int col0 = n0 + wn * 112 + (l & 15);
    #pragma unroll
    for (int ni = 0; ni < 7; ++ni) {
        const int n = col0 + ni * 16;
        const float bn = bias[n];
        #pragma unroll
        for (int mi = 0; mi < 4; ++mi) {
            const int r0 = row0 + mi * 16;
            #pragma unroll
            for (int r = 0; r < 4; ++r)
                C[(size_t)(r0 + r) * N + n] = (acc[mi][ni][r] + bn) * 0.2f;
        }
    }
}

// ================= prep012: merged K1 + K2 + K0 ============================
#define TILE_M 64
#define TILE_N 64
#define TILE_K 16
#define LDS_STRIDE 72
#define NB_K1 416        // 13 x 32 tiles
#define NB_K2 2048
#define NB_K0 25088

__global__ __launch_bounds__(256) void prep012(
    const float* __restrict__ xd, const float* __restrict__ xr,
    const float* __restrict__ Wlp, const float* __restrict__ blp,
    const float* __restrict__ Wnet,
    __hip_bfloat16* __restrict__ Wnet_bf, __hip_bfloat16* __restrict__ x_bf)
{
    const int bid = blockIdx.x;
    const int t = threadIdx.x;

    if (bid < NB_K1) {
        // ---- K1: x_bf[:, :784] = bf16((xd @ Wlp^T + blp - .5)/.2) ----
        __shared__ float As[TILE_K][LDS_STRIDE];
        __shared__ float Bsh[TILE_K][LDS_STRIDE];

        const int bx = bid % 13, by = bid / 13;
        const int tx = t & 15;
        const int ty = t >> 4;
        const int m0 = by * TILE_M;
        const int n0 = bx * TILE_N;
        const int lrow = t >> 2;
        const int lk   = (t & 3) << 2;
        const int Kd = 832, Nd = 784;

        float acc[4][4] = {};

        for (int kt = 0; kt < Kd; kt += TILE_K) {
            float4 av = *(const float4*)(xd + (size_t)(m0 + lrow) * Kd + kt + lk);
            float4 bv = make_float4(0.f, 0.f, 0.f, 0.f);
            if (n0 + lrow < Nd)
                bv = *(const float4*)(Wlp + (size_t)(n0 + lrow) * Kd + kt + lk);

            __syncthreads();
            As[lk + 0][lrow] = av.x; As[lk + 1][lrow] = av.y;
            As[lk + 2][lrow] = av.z; As[lk + 3][lrow] = av.w;
            Bsh[lk + 0][lrow] = bv.x; Bsh[lk + 1][lrow] = bv.y;
            Bsh[lk + 2][lrow] = bv.z; Bsh[lk + 3][lrow] = bv.w;
            __syncthreads();

            #pragma unroll
            for (int k = 0; k < TILE_K; ++k) {
                float4 a = *(const float4*)&As[k][ty << 2];
                float4 b = *(const float4*)&Bsh[k][tx << 2];
                acc[0][0] += a.x * b.x; acc[0][1] += a.x * b.y;
                acc[0][2] += a.x * b.z; acc[0][3] += a.x * b.w;
                acc[1][0] += a.y * b.x; acc[1][1] += a.y * b.y;
                acc[1][2] += a.y * b.z; acc[1][3] += a.y * b.w;
                acc[2][0] += a.z * b.x; acc[2][1] += a.z * b.y;
                acc[2][2] += a.z * b.z; acc[2][3] += a.z * b.w;
                acc[3][0] += a.w * b.x; acc[3][1] += a.w * b.y;
                acc[3][2] += a.w * b.z; acc[3][3] += a.w * b.w;
            }
        }

        #pragma unroll
        for (int j = 0; j < 4; ++j) {
            int n = n0 + (tx << 2) + j;
            if (n < Nd) {
                float bn = blp[n];
                #pragma unroll
                for (int i = 0; i < 4; ++i) {
                    float v = (acc[i][j] + bn - 0.5f) / 0.2f;
                    x_bf[(size_t)(m0 + (ty << 2) + i) * KP + n] =
                        __float2bfloat16(v);
                }
            }
        }
    } else if (bid < NB_K1 + NB_K2) {
        // ---- K2: x_bf[:, 784:1568] = bf16((xr - .5)/.2); pad zeros ----
        const int b = bid - NB_K1;
        if (t < 196) {
            float4 v = *(const float4*)(xr + (size_t)b * 784 + (t << 2));
            __hip_bfloat16 o[4] = {
                __float2bfloat16((v.x - 0.5f) / 0.2f),
                __float2bfloat16((v.y - 0.5f) / 0.2f),
                __float2bfloat16((v.z - 0.5f) / 0.2f),
                __float2bfloat16((v.w - 0.5f) / 0.2f)};
            *(ushort4*)&x_bf[(size_t)b * KP + 784 + (t << 2)] =
                *(const ushort4*)o;
        } else if (t < 204) {
            *(ushort4*)&x_bf[(size_t)b * KP + 1568 + ((t - 196) << 2)] =
                make_ushort4(0, 0, 0, 0);
        }
    } else {
        // ---- K0: Wnet_bf[r][0:1568] = bf16(Wnet[r]); pad zeros ----
        const size_t r = bid - (NB_K1 + NB_K2);
        const float* src = Wnet + r * 1568;
        __hip_bfloat16* dst = Wnet_bf + r * KP;

        for (int i = t; i < 392; i += 256) {
            float4 v = *(const float4*)(src + (i << 2));
            __hip_bfloat16 o[4] = {
                __float2bfloat16(v.x), __float2bfloat16(v.y),
                __float2bfloat16(v.z), __float2bfloat16(v.w)};
            *(ushort4*)&dst[i << 2] = *(const ushort4*)o;
        }
        if (t < 8)
            *(ushort4*)&dst[1568 + (t << 2)] = make_ushort4(0, 0, 0, 0);
    }
}

// ==================== K4a: Gram + Cholesky solve ===========================
// Gram via register-direct MFMA (round-8 version): each wave computes one
// 16x16 quadrant of G = W W^T reading f32 fragments straight from global
// (L3-resident), converting to bf16 in-reg. No LDS staging, no barriers in
// the Gram loop. Then Cholesky + forward substitution.
#define GS_N 32
#define GS_D 784

__device__ __forceinline__ s16x8 cvt8(float4 a, float4 b) {
    __hip_bfloat16 h[8] = {
        __float2bfloat16(a.x), __float2bfloat16(a.y),
        __float2bfloat16(a.z), __float2bfloat16(a.w),
        __float2bfloat16(b.x), __float2bfloat16(b.y),
        __float2bfloat16(b.z), __float2bfloat16(b.w)};
    return *(const s16x8*)h;
}

__global__ __launch_bounds__(256, 4) void gram_solve(
    const float* __restrict__ out, float* __restrict__ Mws)
{
    __shared__ float Gs[GS_N][GS_N + 1];            // 4224 B (G -> L)
    __shared__ float Ms[GS_N][GS_N + 1];            // 4224 B
    __shared__ float Ld[GS_N];

    const int t = threadIdx.x;
    const int l = t & 63;
    const int w = t >> 6;
    const float* row0 = out + (size_t)blockIdx.x * (GS_N * GS_D);

    const int wr = w >> 1, wc2 = w & 1;
    const int ra = wr * 16 + (l & 15);   // Gram row index (A operand)
    const int rb = wc2 * 16 + (l & 15);  // Gram col index (B operand)
    const int kg = l >> 4;               // k-subgroup 0..3

    const float* pa = row0 + (size_t)ra * GS_D + kg * 8;
    const float* pb = row0 + (size_t)rb * GS_D + kg * 8;

    f32x4 acc = {};
    #pragma unroll 2
    for (int s = 0; s < 24; ++s) {       // 24 full K32 steps (768 cols)
        float4 a0 = *(const float4*)(pa + s * 32);
        float4 a1 = *(const float4*)(pa + s * 32 + 4);
        float4 b0 = *(const float4*)(pb + s * 32);
        float4 b1 = *(const float4*)(pb + s * 32 + 4);
        acc = __builtin_amdgcn_mfma_f32_16x16x32_bf16(
            cvt8(a0, a1), cvt8(b0, b1), acc, 0, 0, 0);
    }
    {                                    // tail cols 768..783: kg 0,1 valid
        s16x8 af = {}, bf = {};
        if (kg < 2) {
            float4 a0 = *(const float4*)(pa + 768);
            float4 a1 = *(const float4*)(pa + 768 + 4);
            float4 b0 = *(const float4*)(pb + 768);
            float4 b1 = *(const float4*)(pb + 768 + 4);
            af = cvt8(a0, a1); bf = cvt8(b0, b1);
        }
        acc = __builtin_amdgcn_mfma_f32_16x16x32_bf16(af, bf, acc, 0, 0, 0);
    }

    // C/D layout: col = lane&15, row = (lane>>4)*4 + reg
    {
        const int di = wr * 16 + (l >> 4) * 4;
        const int dj = wc2 * 16 + (l & 15);
        #pragma unroll
        for (int r = 0; r < 4; ++r) Gs[di + r][dj] = acc[r];
    }
    for (int z = t; z < GS_N * (GS_N + 1); z += 256) ((float*)Ms)[z] = 0.f;
    __syncthreads();

    // Cholesky, lower triangle in place (diag in Ld)
    for (int k = 0; k < GS_N; ++k) {
        const float sk = sqrtf(Gs[k][k]);
        if (t == k) Ld[k] = sk;
        if (t > k && t < GS_N) Gs[t][k] /= sk;
        __syncthreads();
        if (t > k && t < GS_N) {
            const float lik = Gs[t][k];
            for (int j = k + 1; j <= t; ++j)
                Gs[t][j] -= lik * Gs[j][k];
        }
        __syncthreads();
    }

    // M = diag(L) * L^-1, column-parallel forward substitution
    if (t < GS_N) {
        const int j = t;
        Ms[j][j] = 1.0f / Ld[j];
        for (int i = j + 1; i < GS_N; ++i) {
            float a = 0.f;
            for (int k = j; k < i; ++k)
                a += Gs[i][k] * Ms[k][j];
            Ms[i][j] = -a / Ld[i];
        }
        for (int i = j + 1; i < GS_N; ++i)
            Ms[i][j] *= Ld[i];
    }
    __syncthreads();

    {
        const int i = t >> 3, j0 = (t & 7) << 2;
        float4 mv = make_float4(Ms[i][j0], Ms[i][j0 + 1],
                                Ms[i][j0 + 2], Ms[i][j0 + 3]);
        *(float4*)(Mws + (size_t)blockIdx.x * 1024 + (t << 2)) = mv;
    }
}

// ======================= K4b: apply correction =============================
// 7x2048 independent blocks (r8 config — measured best). Balanced rows per
// thread-group g = t>>5: {g, 31-g, 15-g, 16+g}; two shared j-loops of
// lengths (31-g) and (16+g) -> uniform 47 iters for every thread.
__global__ __launch_bounds__(256, 8) void gs_apply(
    float* __restrict__ out, const float* __restrict__ Mws)
{
    __shared__ float4 Wf[GS_N][28];     // 14336 B (f32 chunk)
    __shared__ float  Ml[GS_N][36];     // 4608 B (padded for f4 writes)

    const int t = threadIdx.x;
    const int b = blockIdx.y;
    const int k0 = blockIdx.x * 112;
    float* row0 = out + (size_t)b * (GS_N * GS_D);

    {
        float4 mv = *(const float4*)(Mws + (size_t)b * 1024 + (t << 2));
        const int i = t >> 3, j0 = (t & 7) << 2;
        *(float4*)&Ml[i][j0] = mv;
    }
    #pragma unroll
    for (int hh = 0; hh < 4; ++hh) {
        const int h = t + hh * 256;     // 0..1023
        const int r = h >> 5, c = h & 31;
        if (c < 28)
            Wf[r][c] = *(const float4*)(row0 + r * GS_D + k0 + (c << 2));
    }
    __syncthreads();

    const int g  = t >> 5;              // 0..7
    const int c4 = t & 31;              // float4 column
    if (c4 < 28) {
        const int rA = g, rB = 31 - g, rC = 15 - g, rD = 16 + g;
        float4 vA = Wf[rA][c4];
        float4 vB = Wf[rB][c4];
        float4 vC = Wf[rC][c4];
        float4 vD = Wf[rD][c4];
        for (int j = 0; j < rB; ++j) {
            const float4 wj = Wf[j][c4];
            const float mA = (j < rA) ? Ml[rA][j] : 0.f;
            const float mB = Ml[rB][j];
            vA.x += mA * wj.x; vA.y += mA * wj.y;
            vA.z += mA * wj.z; vA.w += mA * wj.w;
            vB.x += mB * wj.x; vB.y += mB * wj.y;
            vB.z += mB * wj.z; vB.w += mB * wj.w;
        }
        for (int j = 0; j < rD; ++j) {
            const float4 wj = Wf[j][c4];
            const float mC = (j < rC) ? Ml[rC][j] : 0.f;
            const float mD = Ml[rD][j];
            vC.x += mC * wj.x; vC.y += mC * wj.y;
            vC.z += mC * wj.z; vC.w += mC * wj.w;
            vD.x += mD * wj.x; vD.y += mD * wj.y;
            vD.z += mD * wj.z; vD.w += mD * wj.w;
        }
        *(float4*)(row0 + rA * GS_D + k0 + (c4 << 2)) = vA;
        *(float4*)(row0 + rB * GS_D + k0 + (c4 << 2)) = vB;
        *(float4*)(row0 + rC * GS_D + k0 + (c4 << 2)) = vC;
        *(float4*)(row0 + rD * GS_D + k0 + (c4 << 2)) = vD;
    }
}

// ================================ launch ===================================
extern "C" void kernel_launch(void* const* d_in, const int* in_sizes, int n_in,
                              void* d_out, int out_size, void* d_ws, size_t ws_size,
                              hipStream_t stream)
{
    const float* xd   = (const float*)d_in[0];  // [2048, 832]
    const float* xr   = (const float*)d_in[1];  // [2048, 1, 28, 28]
    const float* Wlp  = (const float*)d_in[2];  // [784, 832]
    const float* blp  = (const float*)d_in[3];  // [784]
    const float* Wnet = (const float*)d_in[4];  // [25088, 1568]
    const float* bnet = (const float*)d_in[5];  // [25088]
    float* out = (float*)d_out;                 // [2048, 32, 784] f32

    const int B = 2048, OUT = 32 * 784;

    // workspace: [Wnet_bf: 25088*1600*2 = 80.28 MB][x_bf: 2048*1600*2 = 6.55 MB]
    __hip_bfloat16* Wnet_bf = (__hip_bfloat16*)d_ws;
    __hip_bfloat16* x_bf =
        (__hip_bfloat16*)((char*)d_ws + (size_t)OUT * KP * 2);
    // M workspace overlays Wnet_bf region (free after K3; stream-ordered).
    float* Mws = (float*)d_ws;                  // [2048][32][32] f32 = 8.4 MB

    // prep: merged K1 (tiles first) + K2 + K0
    prep012<<<NB_K1 + NB_K2 + NB_K0, 256, 0, stream>>>(
        xd, xr, Wlp, blp, Wnet, Wnet_bf, x_bf);

    // K3: big MFMA GEMM -> d_out (fp32); grid 896 = 8 XCD bands x 112 panels
    gemm_mfma_256<<<dim3(896), 512, 0, stream>>>(
        x_bf, Wnet_bf, bnet, out, B, OUT, KP);

    // K4a: per-batch Gram (register-direct) + Cholesky -> M
    gram_solve<<<B, 256, 0, stream>>>(out, Mws);

    // K4b: apply rank-32 correction in place (7 x 2048 independent blocks)
    gs_apply<<<dim3(7, B), 256, 0, stream>>>(out, Mws);
}